// Round 5
// baseline (52.091 us; speedup 1.0000x reference)
//
#include <hip/hip_runtime.h>
#include <math.h>
#include <stdint.h>

constexpr int Hn = 512, Wn = 512, Bn = 16;
constexpr int GX = 2, GY = 32;       // block = 256 cols x 16 core rows
constexpr int NBLK = GX * GY * Bn;   // 1024 blocks
#define NACC 11
constexpr float NTOT = 16.f * 512.f * 512.f;

// g_acc: 0 bce, 1 sum_d, 2 sum_t, 3 sum_dt, 4..6 cnt(3,5,7), 7..9 bce*mask(3,5,7), 10 detail

__device__ __forceinline__ uint32_t bits4(float4 v) {
    return (uint32_t)(v.x > 0.5f) | ((uint32_t)(v.y > 0.5f) << 1) |
           ((uint32_t)(v.z > 0.5f) << 2) | ((uint32_t)(v.w > 0.5f) << 3);
}

__device__ __forceinline__ float sigm(float x) {
    const float z = __expf(-fabsf(x));
    const float r = __builtin_amdgcn_rcpf(1.f + z);
    return (x >= 0.f) ? r : 1.f - r;
}

__device__ __forceinline__ void px(float xc, float tc, float& dc, float& bc) {
    const float z = __expf(-fabsf(xc));
    const float r = __builtin_amdgcn_rcpf(1.f + z);
    const float p = (xc >= 0.f) ? r : 1.f - r;
    dc = p - tc;
    bc = fmaxf((1.f - 2.f * tc) * xc, 0.f) + __logf(1.f + z);
}

__global__ __launch_bounds__(1024, 8) void crack_main(
    const float* __restrict__ logits, const float* __restrict__ target,
    float* __restrict__ g_acc, unsigned int* __restrict__ g_cnt,
    float* __restrict__ out)
{
    __shared__ uint32_t s_pm[22][64];   // po[0:12) | pu[12:24) per row, per lane
    __shared__ float s_d[18][256];      // d = sigmoid(x)-t, rows y0-1 .. y0+16
    __shared__ float s_dl[16], s_dr[16];
    __shared__ float s_red[16][NACC];

    const int tid = threadIdx.x, lane = tid & 63;
    const int wid = __builtin_amdgcn_readfirstlane(tid >> 6);   // 0..15
    const int x0 = blockIdx.x * 256, y0 = blockIdx.y * 16;
    const size_t base = (size_t)blockIdx.z * (size_t)(Hn * Wn);
    const bool leftE = (x0 == 0), rightE = (x0 + 256 >= Wn);
    const int gx = x0 + 4 * lane;

    uint32_t validm = 0xFFFu;                    // valid cols for erosion complement
    if (leftE && lane == 0)   validm = 0xFF0u;
    if (rightE && lane == 63) validm = 0x0FFu;

    // ---- phase A: horizontal morphology, rows r = wid and r = wid+16 (wid<6) ----
#pragma unroll
    for (int s = 0; s < 2; ++s) {
        const int r = wid + 16 * s;              // wave-uniform
        if (r < 22) {
            const int gy = y0 - 3 + r;
            uint32_t w = 0u, wc = 0u;
            if ((unsigned)gy < (unsigned)Hn) {
                const float* trow = target + base + (size_t)gy * Wn;
                const uint32_t m = bits4(*(const float4*)(trow + gx));
                uint32_t lw = 0u, rw = 0u;
                if (gx >= 4)      lw = bits4(*(const float4*)(trow + gx - 4));
                if (gx + 8 <= Wn) rw = bits4(*(const float4*)(trow + gx + 4));
                w = lw | (m << 4) | (rw << 8);   // bit b = col gx-4+b
                wc = (~w) & validm;
            }
            const uint32_t w1 = w  | (w  << 1) | (w  >> 1);
            const uint32_t w2 = w1 | (w1 << 1) | (w1 >> 1);
            const uint32_t w3 = w2 | (w2 << 1) | (w2 >> 1);
            const uint32_t u1 = wc | (wc << 1) | (wc >> 1);
            const uint32_t u2 = u1 | (u1 << 1) | (u1 >> 1);
            const uint32_t u3 = u2 | (u2 << 1) | (u2 >> 1);
            const uint32_t po = ((w1 >> 4) & 0xFu) | (((w2 >> 4) & 0xFu) << 4) |
                                (((w3 >> 4) & 0xFu) << 8);
            const uint32_t pu = ((u1 >> 4) & 0xFu) | (((u2 >> 4) & 0xFu) << 4) |
                                (((u3 >> 4) & 0xFu) << 8);
            s_pm[r][lane] = po | (pu << 12);
        }
    }

    // ---- phase B: own core row (gy = y0+wid): d, bce, elementwise sums ----
    float4 d4, bce4;
    float sbce, sd, sdt, stt;
    {
        const int gy = y0 + wid;                 // always in [0, 512)
        const float4 x = *(const float4*)(logits + base + (size_t)gy * Wn + gx);
        const float4 t = *(const float4*)(target + base + (size_t)gy * Wn + gx);
        px(x.x, t.x, d4.x, bce4.x); px(x.y, t.y, d4.y, bce4.y);
        px(x.z, t.z, d4.z, bce4.z); px(x.w, t.w, d4.w, bce4.w);
        sbce = bce4.x + bce4.y + bce4.z + bce4.w;
        sd   = d4.x + d4.y + d4.z + d4.w;
        sdt  = d4.x * t.x + d4.y * t.y + d4.z * t.z + d4.w * t.w;
        stt  = t.x + t.y + t.z + t.w;
        *(float4*)&s_d[wid + 1][4 * lane] = d4;
    }
    // halo d rows j=0 (wave 0) and j=17 (wave 15)
    if (wid == 0) {
        const int gy = y0 - 1;
        float4 d = make_float4(0.f, 0.f, 0.f, 0.f);
        if (gy >= 0) {
            const float4 x = *(const float4*)(logits + base + (size_t)gy * Wn + gx);
            const float4 t = *(const float4*)(target + base + (size_t)gy * Wn + gx);
            float b;
            px(x.x, t.x, d.x, b); px(x.y, t.y, d.y, b);
            px(x.z, t.z, d.z, b); px(x.w, t.w, d.w, b);
        }
        *(float4*)&s_d[0][4 * lane] = d;
    }
    if (wid == 15) {
        const int gy = y0 + 16;
        float4 d = make_float4(0.f, 0.f, 0.f, 0.f);
        if (gy < Hn) {
            const float4 x = *(const float4*)(logits + base + (size_t)gy * Wn + gx);
            const float4 t = *(const float4*)(target + base + (size_t)gy * Wn + gx);
            float b;
            px(x.x, t.x, d.x, b); px(x.y, t.y, d.y, b);
            px(x.z, t.z, d.z, b); px(x.w, t.w, d.w, b);
        }
        *(float4*)&s_d[17][4 * lane] = d;
    }
    // edge d columns (x0-1 / x0+256) for core rows, by wave 8
    if (wid == 8) {
        if (lane < 16) {
            float v = 0.f;
            if (!leftE) {
                const int gy = y0 + lane;
                const float xl = logits[base + (size_t)gy * Wn + (x0 - 1)];
                const float tl = target[base + (size_t)gy * Wn + (x0 - 1)];
                v = sigm(xl) - ((tl > 0.5f) ? 1.f : 0.f);
            }
            s_dl[lane] = v;
        } else if (lane >= 32 && lane < 48) {
            float v = 0.f;
            if (!rightE) {
                const int gy = y0 + (lane - 32);
                const float xr = logits[base + (size_t)gy * Wn + (x0 + 256)];
                const float tr = target[base + (size_t)gy * Wn + (x0 + 256)];
                v = sigm(xr) - ((tr > 0.5f) ? 1.f : 0.f);
            }
            s_dr[lane - 32] = v;
        }
    }

    __syncthreads();

    // ---- phase C: vertical combine + Laplacian for core row gy = y0+wid ----
    float sb1 = 0.f, sb2 = 0.f, sb3 = 0.f, sdet = 0.f;
    int c1, c2, c3;
    {
        const uint32_t q0 = s_pm[wid + 0][lane], q1 = s_pm[wid + 1][lane],
                       q2 = s_pm[wid + 2][lane], q3 = s_pm[wid + 3][lane],
                       q4 = s_pm[wid + 4][lane], q5 = s_pm[wid + 5][lane],
                       q6 = s_pm[wid + 6][lane];
        const uint32_t o3 = q2 | q3 | q4;
        const uint32_t o5 = o3 | q1 | q5;
        const uint32_t o7 = o5 | q0 | q6;
        const uint32_t vo = (o3 & 0xFu) | (o5 & 0xF0u) | (o7 & 0xF00u);
        const uint32_t vu = ((o3 >> 12) & 0xFu) | ((o5 >> 12) & 0xF0u) |
                            ((o7 >> 12) & 0xF00u);
        const uint32_t b = vo & vu;              // [0:4) r1, [4:8) r2, [8:12) r3
        c1 = __popc(b & 0xFu);
        c2 = __popc(b & 0xF0u);
        c3 = __popc(b & 0xF00u);
        sb1 = (((b >> 0) & 1) ? bce4.x : 0.f) + (((b >> 1) & 1) ? bce4.y : 0.f) +
              (((b >> 2) & 1) ? bce4.z : 0.f) + (((b >> 3) & 1) ? bce4.w : 0.f);
        sb2 = (((b >> 4) & 1) ? bce4.x : 0.f) + (((b >> 5) & 1) ? bce4.y : 0.f) +
              (((b >> 6) & 1) ? bce4.z : 0.f) + (((b >> 7) & 1) ? bce4.w : 0.f);
        sb3 = (((b >> 8) & 1) ? bce4.x : 0.f) + (((b >> 9) & 1) ? bce4.y : 0.f) +
              (((b >> 10) & 1) ? bce4.z : 0.f) + (((b >> 11) & 1) ? bce4.w : 0.f);

        const float4 du = *(const float4*)&s_d[wid][4 * lane];
        const float4 dd = *(const float4*)&s_d[wid + 2][4 * lane];
        float left = __shfl_up(d4.w, 1);
        { const float el = s_dl[wid]; if (lane == 0)  left = el; }
        float right = __shfl_down(d4.x, 1);
        { const float er = s_dr[wid]; if (lane == 63) right = er; }
        sdet += fabsf(left + d4.y + du.x + dd.x - 4.f * d4.x);
        sdet += fabsf(d4.x + d4.z + du.y + dd.y - 4.f * d4.y);
        sdet += fabsf(d4.y + d4.w + du.z + dd.z - 4.f * d4.z);
        sdet += fabsf(d4.z + right + du.w + dd.w - 4.f * d4.w);
    }

    // ---- reduction: wave shuffle -> LDS -> 11 device atomics -> counter ----
    float acc[NACC];
    acc[0] = sbce; acc[1] = sd; acc[2] = stt; acc[3] = sdt;
    acc[4] = (float)c1; acc[5] = (float)c2; acc[6] = (float)c3;
    acc[7] = sb1; acc[8] = sb2; acc[9] = sb3; acc[10] = sdet;
#pragma unroll
    for (int i = 0; i < NACC; ++i) {
        float v = acc[i];
#pragma unroll
        for (int off = 32; off; off >>= 1) v += __shfl_xor(v, off);
        acc[i] = v;
    }
    if (lane == 0) {
#pragma unroll
        for (int i = 0; i < NACC; ++i) s_red[wid][i] = acc[i];
    }
    __syncthreads();
    if (tid < NACC) {
        float v = 0.f;
#pragma unroll
        for (int w = 0; w < 16; ++w) v += s_red[w][tid];
        atomicAdd(&g_acc[tid], v);
    }
    if (tid == 0) {
        __threadfence();
        const unsigned int old = atomicAdd(g_cnt, 1u);
        if (old == (unsigned int)(NBLK - 1)) {
            // last block: finalize (device-scope atomic reads see all prior adds)
            float t[NACC];
#pragma unroll
            for (int i = 0; i < NACC; ++i) t[i] = atomicAdd(&g_acc[i], 0.f);
            const float bce   = t[0] / NTOT;
            const float st    = t[2];
            const float sp    = t[1] + t[2];
            const float inter = t[3] + t[2];
            const float dice = 1.f - (2.f * inter + 1.f) / (sp + st + 1.f);
            const float fp = sp - inter, fn = st - inter;
            const float tvi = (inter + 1.f) / (inter + 0.6f * fp + 0.4f * fn + 1.f);
            const float tversky = powf(fmaxf(1.f - tvi, 0.f), 0.75f);
            float tb = 0.f, ns = 0.f;
            for (int i = 0; i < 3; ++i) {
                const float cnt = t[4 + i], sb = t[7 + i];
                if (cnt >= 1.f) { tb += sb / cnt; ns += 1.f; }
            }
            const float boundary = (ns > 0.f) ? tb / ns : 0.f;
            const float detail = t[10] / NTOT;
            out[0] = bce + dice + 0.5f * tversky + 0.5f * boundary + 0.3f * detail;
        }
    }
}

extern "C" void kernel_launch(void* const* d_in, const int* in_sizes, int n_in,
                              void* d_out, int out_size, void* d_ws, size_t ws_size,
                              hipStream_t stream) {
    const float* logits = (const float*)d_in[0];
    const float* target = (const float*)d_in[1];
    float* g_acc = (float*)d_ws;                       // 11 floats
    unsigned int* g_cnt = (unsigned int*)d_ws + NACC;  // 1 uint

    hipMemsetAsync(d_ws, 0, 64, stream);
    dim3 grid(GX, GY, Bn);
    crack_main<<<grid, dim3(1024), 0, stream>>>(logits, target, g_acc, g_cnt,
                                                (float*)d_out);
}

// Round 6
// 43.584 us; speedup vs baseline: 1.1952x; 1.1952x over previous
//
#include <hip/hip_runtime.h>
#include <math.h>
#include <stdint.h>

constexpr int Hn = 512, Wn = 512, Bn = 16;
constexpr int GX = 2, GY = 32;       // block = 256 cols x 16 core rows
constexpr int NBLK = GX * GY * Bn;   // 1024 blocks
#define NACC 11
constexpr int REP = 32, PAD = 16;    // 32 replica rows, 64B apart
constexpr float NTOT = 16.f * 512.f * 512.f;

// g_part[rep][i]: i = 0 bce, 1 sum_d, 2 sum_t, 3 sum_dt,
//                 4..6 cnt(3,5,7), 7..9 bce*mask(3,5,7), 10 detail

__device__ __forceinline__ uint32_t bits4(float4 v) {
    return (uint32_t)(v.x > 0.5f) | ((uint32_t)(v.y > 0.5f) << 1) |
           ((uint32_t)(v.z > 0.5f) << 2) | ((uint32_t)(v.w > 0.5f) << 3);
}

__device__ __forceinline__ float sigm(float x) {
    const float z = __expf(-fabsf(x));
    const float r = __builtin_amdgcn_rcpf(1.f + z);
    return (x >= 0.f) ? r : 1.f - r;
}

__device__ __forceinline__ void px(float xc, float tc, float& dc, float& bc) {
    const float z = __expf(-fabsf(xc));
    const float r = __builtin_amdgcn_rcpf(1.f + z);
    const float p = (xc >= 0.f) ? r : 1.f - r;
    dc = p - tc;
    bc = fmaxf((1.f - 2.f * tc) * xc, 0.f) + __logf(1.f + z);
}

__global__ __launch_bounds__(1024, 8) void crack_main(
    const float* __restrict__ logits, const float* __restrict__ target,
    float* __restrict__ g_part, unsigned int* __restrict__ g_cnt,
    float* __restrict__ out)
{
    __shared__ uint32_t s_pm[22][64];   // po[0:12) | pu[12:24) per row, per lane
    __shared__ float s_d[18][256];      // d = sigmoid(x)-t, rows y0-1 .. y0+16
    __shared__ float s_dl[16], s_dr[16];
    __shared__ float s_red[16][NACC];
    __shared__ float s_sum[NACC];
    __shared__ unsigned int s_last;

    const int tid = threadIdx.x, lane = tid & 63;
    const int wid = __builtin_amdgcn_readfirstlane(tid >> 6);   // 0..15
    const int x0 = blockIdx.x * 256, y0 = blockIdx.y * 16;
    const size_t base = (size_t)blockIdx.z * (size_t)(Hn * Wn);
    const bool leftE = (x0 == 0), rightE = (x0 + 256 >= Wn);
    const int gx = x0 + 4 * lane;
    const int bid = (blockIdx.z * GY + blockIdx.y) * GX + blockIdx.x;

    uint32_t validm = 0xFFFu;                    // valid cols for erosion complement
    if (leftE && lane == 0)   validm = 0xFF0u;
    if (rightE && lane == 63) validm = 0x0FFu;

    // ---- phase A: horizontal morphology, rows r = wid and r = wid+16 (wid<6) ----
#pragma unroll
    for (int s = 0; s < 2; ++s) {
        const int r = wid + 16 * s;              // wave-uniform
        if (r < 22) {
            const int gy = y0 - 3 + r;
            uint32_t w = 0u, wc = 0u;
            if ((unsigned)gy < (unsigned)Hn) {
                const float* trow = target + base + (size_t)gy * Wn;
                const uint32_t m = bits4(*(const float4*)(trow + gx));
                uint32_t lw = 0u, rw = 0u;
                if (gx >= 4)      lw = bits4(*(const float4*)(trow + gx - 4));
                if (gx + 8 <= Wn) rw = bits4(*(const float4*)(trow + gx + 4));
                w = lw | (m << 4) | (rw << 8);   // bit b = col gx-4+b
                wc = (~w) & validm;
            }
            const uint32_t w1 = w  | (w  << 1) | (w  >> 1);
            const uint32_t w2 = w1 | (w1 << 1) | (w1 >> 1);
            const uint32_t w3 = w2 | (w2 << 1) | (w2 >> 1);
            const uint32_t u1 = wc | (wc << 1) | (wc >> 1);
            const uint32_t u2 = u1 | (u1 << 1) | (u1 >> 1);
            const uint32_t u3 = u2 | (u2 << 1) | (u2 >> 1);
            const uint32_t po = ((w1 >> 4) & 0xFu) | (((w2 >> 4) & 0xFu) << 4) |
                                (((w3 >> 4) & 0xFu) << 8);
            const uint32_t pu = ((u1 >> 4) & 0xFu) | (((u2 >> 4) & 0xFu) << 4) |
                                (((u3 >> 4) & 0xFu) << 8);
            s_pm[r][lane] = po | (pu << 12);
        }
    }

    // ---- phase B: own core row (gy = y0+wid): d, bce, elementwise sums ----
    float4 d4, bce4;
    float sbce, sd, sdt, stt;
    {
        const int gy = y0 + wid;                 // always in [0, 512)
        const float4 x = *(const float4*)(logits + base + (size_t)gy * Wn + gx);
        const float4 t = *(const float4*)(target + base + (size_t)gy * Wn + gx);
        px(x.x, t.x, d4.x, bce4.x); px(x.y, t.y, d4.y, bce4.y);
        px(x.z, t.z, d4.z, bce4.z); px(x.w, t.w, d4.w, bce4.w);
        sbce = bce4.x + bce4.y + bce4.z + bce4.w;
        sd   = d4.x + d4.y + d4.z + d4.w;
        sdt  = d4.x * t.x + d4.y * t.y + d4.z * t.z + d4.w * t.w;
        stt  = t.x + t.y + t.z + t.w;
        *(float4*)&s_d[wid + 1][4 * lane] = d4;
    }
    // halo d rows j=0 (wave 0) and j=17 (wave 15)
    if (wid == 0) {
        const int gy = y0 - 1;
        float4 d = make_float4(0.f, 0.f, 0.f, 0.f);
        if (gy >= 0) {
            const float4 x = *(const float4*)(logits + base + (size_t)gy * Wn + gx);
            const float4 t = *(const float4*)(target + base + (size_t)gy * Wn + gx);
            float b;
            px(x.x, t.x, d.x, b); px(x.y, t.y, d.y, b);
            px(x.z, t.z, d.z, b); px(x.w, t.w, d.w, b);
        }
        *(float4*)&s_d[0][4 * lane] = d;
    }
    if (wid == 15) {
        const int gy = y0 + 16;
        float4 d = make_float4(0.f, 0.f, 0.f, 0.f);
        if (gy < Hn) {
            const float4 x = *(const float4*)(logits + base + (size_t)gy * Wn + gx);
            const float4 t = *(const float4*)(target + base + (size_t)gy * Wn + gx);
            float b;
            px(x.x, t.x, d.x, b); px(x.y, t.y, d.y, b);
            px(x.z, t.z, d.z, b); px(x.w, t.w, d.w, b);
        }
        *(float4*)&s_d[17][4 * lane] = d;
    }
    // edge d columns (x0-1 / x0+256) for core rows, by wave 8
    if (wid == 8) {
        if (lane < 16) {
            float v = 0.f;
            if (!leftE) {
                const int gy = y0 + lane;
                const float xl = logits[base + (size_t)gy * Wn + (x0 - 1)];
                const float tl = target[base + (size_t)gy * Wn + (x0 - 1)];
                v = sigm(xl) - ((tl > 0.5f) ? 1.f : 0.f);
            }
            s_dl[lane] = v;
        } else if (lane >= 32 && lane < 48) {
            float v = 0.f;
            if (!rightE) {
                const int gy = y0 + (lane - 32);
                const float xr = logits[base + (size_t)gy * Wn + (x0 + 256)];
                const float tr = target[base + (size_t)gy * Wn + (x0 + 256)];
                v = sigm(xr) - ((tr > 0.5f) ? 1.f : 0.f);
            }
            s_dr[lane - 32] = v;
        }
    }

    __syncthreads();

    // ---- phase C: vertical combine + Laplacian for core row gy = y0+wid ----
    float sb1 = 0.f, sb2 = 0.f, sb3 = 0.f, sdet = 0.f;
    int c1, c2, c3;
    {
        const uint32_t q0 = s_pm[wid + 0][lane], q1 = s_pm[wid + 1][lane],
                       q2 = s_pm[wid + 2][lane], q3 = s_pm[wid + 3][lane],
                       q4 = s_pm[wid + 4][lane], q5 = s_pm[wid + 5][lane],
                       q6 = s_pm[wid + 6][lane];
        const uint32_t o3 = q2 | q3 | q4;
        const uint32_t o5 = o3 | q1 | q5;
        const uint32_t o7 = o5 | q0 | q6;
        const uint32_t vo = (o3 & 0xFu) | (o5 & 0xF0u) | (o7 & 0xF00u);
        const uint32_t vu = ((o3 >> 12) & 0xFu) | ((o5 >> 12) & 0xF0u) |
                            ((o7 >> 12) & 0xF00u);
        const uint32_t b = vo & vu;              // [0:4) r1, [4:8) r2, [8:12) r3
        c1 = __popc(b & 0xFu);
        c2 = __popc(b & 0xF0u);
        c3 = __popc(b & 0xF00u);
        sb1 = (((b >> 0) & 1) ? bce4.x : 0.f) + (((b >> 1) & 1) ? bce4.y : 0.f) +
              (((b >> 2) & 1) ? bce4.z : 0.f) + (((b >> 3) & 1) ? bce4.w : 0.f);
        sb2 = (((b >> 4) & 1) ? bce4.x : 0.f) + (((b >> 5) & 1) ? bce4.y : 0.f) +
              (((b >> 6) & 1) ? bce4.z : 0.f) + (((b >> 7) & 1) ? bce4.w : 0.f);
        sb3 = (((b >> 8) & 1) ? bce4.x : 0.f) + (((b >> 9) & 1) ? bce4.y : 0.f) +
              (((b >> 10) & 1) ? bce4.z : 0.f) + (((b >> 11) & 1) ? bce4.w : 0.f);

        const float4 du = *(const float4*)&s_d[wid][4 * lane];
        const float4 dd = *(const float4*)&s_d[wid + 2][4 * lane];
        float left = __shfl_up(d4.w, 1);
        { const float el = s_dl[wid]; if (lane == 0)  left = el; }
        float right = __shfl_down(d4.x, 1);
        { const float er = s_dr[wid]; if (lane == 63) right = er; }
        sdet += fabsf(left + d4.y + du.x + dd.x - 4.f * d4.x);
        sdet += fabsf(d4.x + d4.z + du.y + dd.y - 4.f * d4.y);
        sdet += fabsf(d4.y + d4.w + du.z + dd.z - 4.f * d4.z);
        sdet += fabsf(d4.z + right + du.w + dd.w - 4.f * d4.w);
    }

    // ---- reduction: wave shuffle -> LDS -> replicated device atomics ----
    float acc[NACC];
    acc[0] = sbce; acc[1] = sd; acc[2] = stt; acc[3] = sdt;
    acc[4] = (float)c1; acc[5] = (float)c2; acc[6] = (float)c3;
    acc[7] = sb1; acc[8] = sb2; acc[9] = sb3; acc[10] = sdet;
#pragma unroll
    for (int i = 0; i < NACC; ++i) {
        float v = acc[i];
#pragma unroll
        for (int off = 32; off; off >>= 1) v += __shfl_xor(v, off);
        acc[i] = v;
    }
    if (lane == 0) {
#pragma unroll
        for (int i = 0; i < NACC; ++i) s_red[wid][i] = acc[i];
    }
    __syncthreads();
    if (tid < NACC) {
        float v = 0.f;
#pragma unroll
        for (int w = 0; w < 16; ++w) v += s_red[w][tid];
        atomicAdd(&g_part[(bid & (REP - 1)) * PAD + tid], v);
    }
    if (tid == 0) {
        __threadfence();   // wave 0's atomics drained (vmcnt is per-wave)
        s_last = (atomicAdd(g_cnt, 1u) == (unsigned int)(NBLK - 1)) ? 1u : 0u;
    }
    __syncthreads();

    // ---- last block: coherent parallel read of replicas + finalize ----
    if (s_last) {
        if (tid < NACC) s_sum[tid] = 0.f;
        __syncthreads();
        const int rep = tid >> 4, slot = tid & 15;
        if (rep < REP && slot < NACC) {
            const float v = atomicAdd(&g_part[rep * PAD + slot], 0.f); // RMW read
            atomicAdd(&s_sum[slot], v);
        }
        __syncthreads();
        if (tid == 0) {
            float t[NACC];
#pragma unroll
            for (int i = 0; i < NACC; ++i) t[i] = s_sum[i];
            const float bce   = t[0] / NTOT;
            const float st    = t[2];
            const float sp    = t[1] + t[2];
            const float inter = t[3] + t[2];
            const float dice = 1.f - (2.f * inter + 1.f) / (sp + st + 1.f);
            const float fp = sp - inter, fn = st - inter;
            const float tvi = (inter + 1.f) / (inter + 0.6f * fp + 0.4f * fn + 1.f);
            const float tversky = powf(fmaxf(1.f - tvi, 0.f), 0.75f);
            float tb = 0.f, ns = 0.f;
            for (int i = 0; i < 3; ++i) {
                const float cnt = t[4 + i], sb = t[7 + i];
                if (cnt >= 1.f) { tb += sb / cnt; ns += 1.f; }
            }
            const float boundary = (ns > 0.f) ? tb / ns : 0.f;
            const float detail = t[10] / NTOT;
            out[0] = bce + dice + 0.5f * tversky + 0.5f * boundary + 0.3f * detail;
        }
    }
}

extern "C" void kernel_launch(void* const* d_in, const int* in_sizes, int n_in,
                              void* d_out, int out_size, void* d_ws, size_t ws_size,
                              hipStream_t stream) {
    const float* logits = (const float*)d_in[0];
    const float* target = (const float*)d_in[1];
    float* g_part = (float*)d_ws;                            // REP*PAD floats
    unsigned int* g_cnt = (unsigned int*)((char*)d_ws + REP * PAD * sizeof(float));

    hipMemsetAsync(d_ws, 0, REP * PAD * sizeof(float) + 64, stream);
    dim3 grid(GX, GY, Bn);
    crack_main<<<grid, dim3(1024), 0, stream>>>(logits, target, g_part, g_cnt,
                                                (float*)d_out);
}